// Round 3
// baseline (390.660 us; speedup 1.0000x reference)
//
#include <hip/hip_runtime.h>

#define NN 100000
#define NE 800000

// ---- workspace layout (bytes) ----
#define OFF_DEG      0u           // int[2N]
#define OFF_INV      800000u      // float[2N]   [0,N)=out_inv(row), [N,2N)=in_inv(col)
#define OFF_OFFS     1600000u     // int[2N+1]
#define OFF_CURS     2400016u     // int[2N]
#define OFF_BSUMS    3200016u     // int[256]
#define OFF_BBASE    3201040u     // int[260]
#define OFF_CSRC     3202080u     // int[2E]  (src indices only; weights recomputed in gather)
#define OFF_XB       9602080u     // bf16[N*128]
#define OFF_AGG      35202080u    // bf16[N*256]  (cols 0..127 = agg_in, 128..255 = agg_out)
#define OFF_WT       86402080u    // bf16[128*256] WT[c][k]: k<128 -> W_ds, else W_sd
#define OFF_BIAS     86467616u    // float[128]   0.5*(b_ds+b_sd)

#define SCAN_BLOCKS 196   // ceil(2N/1024)

typedef short short8 __attribute__((ext_vector_type(8)));
typedef float f32x4 __attribute__((ext_vector_type(4)));

__device__ __forceinline__ unsigned short f2bf(float f) {
    unsigned u = __float_as_uint(f);
    u = (u + 0x7FFFu + ((u >> 16) & 1u)) >> 16;   // RNE
    return (unsigned short)u;
}
__device__ __forceinline__ float b2f(unsigned short h) {
    return __uint_as_float(((unsigned)h) << 16);
}

__global__ void k_deg(const int* __restrict__ ei, int* __restrict__ deg) {
    int e = blockIdx.x * blockDim.x + threadIdx.x;
    if (e < NE) {
        atomicAdd(&deg[ei[e]], 1);            // row occurrences (out-deg)
        atomicAdd(&deg[NN + ei[NE + e]], 1);  // col occurrences (in-deg)
    }
}

__global__ void k_scan1(const int* __restrict__ deg, float* __restrict__ inv,
                        int* __restrict__ bsums) {
    __shared__ int sdata[256];
    int base = blockIdx.x * 1024;
    int tsum = 0;
    for (int j = 0; j < 4; ++j) {
        int i = base + threadIdx.x * 4 + j;
        if (i < 2 * NN) {
            int d = deg[i];
            inv[i] = (d > 0) ? rsqrtf((float)d) : 0.0f;
            tsum += d;
        }
    }
    sdata[threadIdx.x] = tsum;
    __syncthreads();
    for (int s = 128; s > 0; s >>= 1) {
        if (threadIdx.x < s) sdata[threadIdx.x] += sdata[threadIdx.x + s];
        __syncthreads();
    }
    if (threadIdx.x == 0) bsums[blockIdx.x] = sdata[0];
}

__global__ void k_scan2(const int* __restrict__ bsums, int* __restrict__ bbase, int nb) {
    if (threadIdx.x == 0) {
        int run = 0;
        for (int b = 0; b < nb; ++b) { bbase[b] = run; run += bsums[b]; }
        bbase[nb] = run;
    }
}

__global__ void k_scan3(const int* __restrict__ deg, const int* __restrict__ bbase,
                        int* __restrict__ offsets, int* __restrict__ cursor) {
    __shared__ int sdata[256];
    int base = blockIdx.x * 1024;
    int vals[4];
    int tsum = 0;
    for (int j = 0; j < 4; ++j) {
        int i = base + threadIdx.x * 4 + j;
        vals[j] = (i < 2 * NN) ? deg[i] : 0;
        tsum += vals[j];
    }
    sdata[threadIdx.x] = tsum;
    __syncthreads();
    for (int s = 1; s < 256; s <<= 1) {
        int v = (threadIdx.x >= (unsigned)s) ? sdata[threadIdx.x - s] : 0;
        __syncthreads();
        sdata[threadIdx.x] += v;
        __syncthreads();
    }
    int excl = bbase[blockIdx.x] + ((threadIdx.x > 0) ? sdata[threadIdx.x - 1] : 0);
    for (int j = 0; j < 4; ++j) {
        int i = base + threadIdx.x * 4 + j;
        if (i < 2 * NN) {
            offsets[i] = excl;
            cursor[i]  = excl;
            excl += vals[j];
        }
    }
    if (blockIdx.x == 0 && threadIdx.x == 0) offsets[2 * NN] = 2 * NE;
}

// scatter src indices only (weights recomputed at gather time)
__global__ void k_fill(const int* __restrict__ ei, int* __restrict__ cursor,
                       int* __restrict__ csr_src) {
    int e = blockIdx.x * blockDim.x + threadIdx.x;
    if (e >= NE) return;
    int r = ei[e];
    int c = ei[NE + e];
    int p1 = atomicAdd(&cursor[r], 1);       // keyed by row -> in-aggregation sources
    csr_src[p1] = c;
    int p2 = atomicAdd(&cursor[NN + c], 1);  // keyed by col -> out-aggregation sources
    csr_src[p2] = r;
}

// x fp32 -> bf16
__global__ __launch_bounds__(256) void k_cvt_x(const float4* __restrict__ x4,
                                               ushort4* __restrict__ xb4) {
    int i = blockIdx.x * blockDim.x + threadIdx.x;
    if (i >= NN * 32) return;
    float4 v = x4[i];
    ushort4 o;
    o.x = f2bf(v.x); o.y = f2bf(v.y); o.z = f2bf(v.z); o.w = f2bf(v.w);
    xb4[i] = o;
}

// Build WT[c][k] (bf16) and fused bias
__global__ void k_prep_w(const float* __restrict__ Wds, const float* __restrict__ Wsd,
                         const float* __restrict__ bds, const float* __restrict__ bsd,
                         unsigned short* __restrict__ wt, float* __restrict__ bias) {
    int id = blockIdx.x * blockDim.x + threadIdx.x;
    if (id >= 128 * 256) return;
    int c = id & 127;
    int k = id >> 7;
    float v = (k < 128) ? Wds[k * 128 + c] : Wsd[(k - 128) * 128 + c];
    wt[c * 256 + k] = f2bf(v);
    if (k == 0) bias[c] = 0.5f * (bds[c] + bsd[c]);
}

// One 64-lane wave per node: lanes 0-31 = in-direction, 32-63 = out-direction.
// Cooperative CSR load (32 entries/shot) + shfl broadcast removes the
// dependent-address chain from the row-load stream.
__global__ __launch_bounds__(256) void k_gather(
    const ushort4* __restrict__ xb4, const int* __restrict__ offsets,
    const int* __restrict__ csr_src, const float* __restrict__ inv,
    ushort4* __restrict__ agg4) {
    int wave = threadIdx.x >> 6;
    int lane = threadIdx.x & 63;
    int n = blockIdx.x * 4 + wave;
    if (n >= NN) return;
    int grp = lane >> 5;         // 0 = in-agg (keyed by row), 1 = out-agg (keyed by col)
    int cl = lane & 31;

    int key = grp * NN + n;
    int s0 = offsets[key], s1 = offsets[key + 1];

    float4 acc = {0.f, 0.f, 0.f, 0.f};
    for (int base = s0; base < s1; base += 32) {
        int len = s1 - base;
        if (len > 32) len = 32;
        int src_cl = 0;
        float w_cl = 0.f;
        if (cl < len) {
            src_cl = csr_src[base + cl];
            w_cl = inv[(grp ^ 1) * NN + src_cl];   // source-side scale
        }
        for (int j = 0; j < len; ++j) {
            int src = __shfl(src_cl, j, 32);
            float w = __shfl(w_cl, j, 32);
            ushort4 v = xb4[src * 32 + cl];
            acc.x += w * b2f(v.x); acc.y += w * b2f(v.y);
            acc.z += w * b2f(v.z); acc.w += w * b2f(v.w);
        }
    }

    float ds = 0.5f * inv[grp * NN + n];           // dest-side scale + ALPHA fold
    ushort4 o;
    o.x = f2bf(acc.x * ds); o.y = f2bf(acc.y * ds);
    o.z = f2bf(acc.z * ds); o.w = f2bf(acc.w * ds);
    agg4[n * 64 + grp * 32 + cl] = o;
}

// out[N][128] = agg[N][256](bf16) @ WT^T (K=256) + bias
__global__ __launch_bounds__(256) void k_gemm_mfma(
    const unsigned short* __restrict__ agg, const unsigned short* __restrict__ wt,
    const float* __restrict__ bias, float* __restrict__ out) {
    const int wave = threadIdx.x >> 6;
    const int lane = threadIdx.x & 63;
    const int row0 = blockIdx.x * 64 + wave * 16;
    const int fr = lane & 15;
    const int kg = (lane >> 4) * 8;

    int arow = row0 + fr;
    if (arow >= NN) arow = 0;
    const unsigned short* aptr = agg + arow * 256 + kg;

    f32x4 acc[8] = {};

#pragma unroll
    for (int s = 0; s < 8; ++s) {
        short8 afrag = *(const short8*)(aptr + s * 32);
#pragma unroll
        for (int t = 0; t < 8; ++t) {
            short8 bfrag = *(const short8*)(wt + (t * 16 + fr) * 256 + s * 32 + kg);
            acc[t] = __builtin_amdgcn_mfma_f32_16x16x32_bf16(afrag, bfrag, acc[t], 0, 0, 0);
        }
    }

    const int orow0 = row0 + (lane >> 4) * 4;
#pragma unroll
    for (int i = 0; i < 4; ++i) {
        int orow = orow0 + i;
        if (orow < NN) {
#pragma unroll
            for (int t = 0; t < 8; ++t) {
                int col = t * 16 + fr;
                out[orow * 128 + col] = acc[t][i] + bias[col];
            }
        }
    }
}

extern "C" void kernel_launch(void* const* d_in, const int* in_sizes, int n_in,
                              void* d_out, int out_size, void* d_ws, size_t ws_size,
                              hipStream_t stream) {
    const float* x   = (const float*)d_in[0];
    const int* ei    = (const int*)d_in[1];
    const float* Wsd = (const float*)d_in[2];
    const float* bsd = (const float*)d_in[3];
    const float* Wds = (const float*)d_in[4];
    const float* bds = (const float*)d_in[5];

    char* ws = (char*)d_ws;
    int*   deg     = (int*)(ws + OFF_DEG);
    float* inv     = (float*)(ws + OFF_INV);
    int*   offsets = (int*)(ws + OFF_OFFS);
    int*   cursor  = (int*)(ws + OFF_CURS);
    int*   bsums   = (int*)(ws + OFF_BSUMS);
    int*   bbase   = (int*)(ws + OFF_BBASE);
    int*   csr_src = (int*)(ws + OFF_CSRC);
    unsigned short* xb  = (unsigned short*)(ws + OFF_XB);
    unsigned short* agg = (unsigned short*)(ws + OFF_AGG);
    unsigned short* wt  = (unsigned short*)(ws + OFF_WT);
    float* bias    = (float*)(ws + OFF_BIAS);

    hipMemsetAsync(deg, 0, 2 * NN * sizeof(int), stream);

    k_deg<<<(NE + 255) / 256, 256, 0, stream>>>(ei, deg);
    k_cvt_x<<<(NN * 32 + 255) / 256, 256, 0, stream>>>((const float4*)x, (ushort4*)xb);
    k_prep_w<<<(128 * 256 + 255) / 256, 256, 0, stream>>>(Wds, Wsd, bds, bsd, wt, bias);
    k_scan1<<<SCAN_BLOCKS, 256, 0, stream>>>(deg, inv, bsums);
    k_scan2<<<1, 64, 0, stream>>>(bsums, bbase, SCAN_BLOCKS);
    k_scan3<<<SCAN_BLOCKS, 256, 0, stream>>>(deg, bbase, offsets, cursor);
    k_fill<<<(NE + 255) / 256, 256, 0, stream>>>(ei, cursor, csr_src);
    k_gather<<<(NN + 3) / 4, 256, 0, stream>>>((const ushort4*)xb, offsets, csr_src, inv,
                                               (ushort4*)agg);
    k_gemm_mfma<<<(NN + 63) / 64, 256, 0, stream>>>(agg, wt, bias, (float*)d_out);
}

// Round 4
// 261.943 us; speedup vs baseline: 1.4914x; 1.4914x over previous
//
#include <hip/hip_runtime.h>

#define NN 100000
#define NE 800000
#define NI 1600000      // items = 2E (both directions)
#define NB 391          // coarse buckets = ceil(2N / 512)
#define IPB 6250        // items per block in hist/scatter (256 blocks)

// ---- workspace layout (bytes) ----
#define OFF_INV    0u           // float[2N]   [0,N)=out_inv(row), [N,2N)=in_inv(col)
#define OFF_OFFS   800000u      // int[2N+1]
#define OFF_BB     1600008u     // int[NB+1]
#define OFF_HIST   1601600u     // int[NB*256]
#define OFF_CSRC   2001984u     // int[2E]
#define OFF_XB     8401984u     // bf16[N*128]
#define OFF_AGG    34001984u    // bf16[N*256] (cols 0..127 = agg_in, 128..255 = agg_out)
#define OFF_PAIRS  34001984u    // ulong[2E] — aliases AGG (dead before k_gather writes agg)
#define OFF_WT     85201984u    // bf16[128*256] WT[c][k]: k<128 -> W_ds, else W_sd
#define OFF_BIAS   85267520u    // float[128] 0.5*(b_ds+b_sd)

typedef short short8 __attribute__((ext_vector_type(8)));
typedef float f32x4 __attribute__((ext_vector_type(4)));

__device__ __forceinline__ unsigned short f2bf(float f) {
    unsigned u = __float_as_uint(f);
    u = (u + 0x7FFFu + ((u >> 16) & 1u)) >> 16;   // RNE
    return (unsigned short)u;
}
__device__ __forceinline__ float b2f(unsigned short h) {
    return __uint_as_float(((unsigned)h) << 16);
}

// item i: i<NE  -> key=row=ei[i],     val=col=ei[NE+i]   (in-agg, keyed by row)
//         i>=NE -> key=NN+col=NN+ei[i], val=row=ei[i-NE] (out-agg, keyed by col)

__global__ __launch_bounds__(256) void k_hist(const int* __restrict__ ei,
                                              int* __restrict__ hist) {
    __shared__ int h[NB];
    for (int k = threadIdx.x; k < NB; k += 256) h[k] = 0;
    __syncthreads();
    int base = blockIdx.x * IPB;
    for (int t = threadIdx.x; t < IPB; t += 256) {
        int i = base + t;
        int key = (i < NE) ? ei[i] : (NN + ei[i]);
        atomicAdd(&h[key >> 9], 1);
    }
    __syncthreads();
    for (int k = threadIdx.x; k < NB; k += 256) hist[k * 256 + blockIdx.x] = h[k];
}

__global__ void k_scanbase(int* __restrict__ hist, int* __restrict__ bb) {
    __shared__ int tot[NB];
    int tid = threadIdx.x;
    for (int k = tid; k < NB; k += 256) {
        int s = 0;
        const int* p = hist + k * 256;
        for (int b = 0; b < 256; ++b) s += p[b];
        tot[k] = s;
    }
    __syncthreads();
    if (tid == 0) {
        int run = 0;
        for (int k = 0; k < NB; ++k) { bb[k] = run; int t = tot[k]; tot[k] = run; run += t; }
        bb[NB] = run;
    }
    __syncthreads();
    for (int k = tid; k < NB; k += 256) {
        int run = tot[k];
        int* p = hist + k * 256;
        for (int b = 0; b < 256; ++b) { int t = p[b]; p[b] = run; run += t; }
    }
}

__global__ __launch_bounds__(256) void k_scatter(const int* __restrict__ ei,
                                                 const int* __restrict__ hist,
                                                 unsigned long long* __restrict__ pairs) {
    __shared__ int cur[NB];
    for (int k = threadIdx.x; k < NB; k += 256) cur[k] = hist[k * 256 + blockIdx.x];
    __syncthreads();
    int base = blockIdx.x * IPB;
    for (int t = threadIdx.x; t < IPB; t += 256) {
        int i = base + t;
        int e = ei[i];
        int key, val;
        if (i < NE) { key = e;      val = ei[NE + i]; }
        else        { key = NN + e; val = ei[i - NE]; }
        int pos = atomicAdd(&cur[key >> 9], 1);
        pairs[pos] = (((unsigned long long)(unsigned)key) << 32) | (unsigned)val;
    }
}

// one block per bucket: count 512 local keys, scan, emit offsets+inv, scatter vals
__global__ __launch_bounds__(256) void k_bucket(const unsigned long long* __restrict__ pairs,
                                                const int* __restrict__ bb,
                                                int* __restrict__ csr_src,
                                                int* __restrict__ offsets,
                                                float* __restrict__ inv) {
    __shared__ int sA[512], sB[512], cur[512];
    const int h = blockIdx.x, tid = threadIdx.x;
    const int s0 = bb[h], s1 = bb[h + 1];
    for (int k = tid; k < 512; k += 256) sA[k] = 0;
    __syncthreads();
    for (int i = s0 + tid; i < s1; i += 256) {
        int key = (int)(pairs[i] >> 32);
        atomicAdd(&sA[key & 511], 1);
    }
    __syncthreads();
    int *src = sA, *dst = sB;
    for (int st = 1; st < 512; st <<= 1) {
        for (int k = tid; k < 512; k += 256) dst[k] = src[k] + ((k >= st) ? src[k - st] : 0);
        __syncthreads();
        int* tp = src; src = dst; dst = tp;
    }
    // src = inclusive scan
    for (int k = tid; k < 512; k += 256) {
        int incl = src[k];
        int excl = (k > 0) ? src[k - 1] : 0;
        cur[k] = s0 + excl;
        int gkey = h * 512 + k;
        if (gkey <= 2 * NN) offsets[gkey] = s0 + excl;
        if (gkey < 2 * NN) {
            int cnt = incl - excl;
            inv[gkey] = (cnt > 0) ? rsqrtf((float)cnt) : 0.0f;
        }
    }
    __syncthreads();
    for (int i = s0 + tid; i < s1; i += 256) {
        unsigned long long p = pairs[i];
        int key = (int)(p >> 32);
        int pos = atomicAdd(&cur[key & 511], 1);
        csr_src[pos] = (int)(unsigned)(p & 0xffffffffULL);
    }
}

// x fp32 -> bf16
__global__ __launch_bounds__(256) void k_cvt_x(const float4* __restrict__ x4,
                                               ushort4* __restrict__ xb4) {
    int i = blockIdx.x * blockDim.x + threadIdx.x;
    if (i >= NN * 32) return;
    float4 v = x4[i];
    ushort4 o;
    o.x = f2bf(v.x); o.y = f2bf(v.y); o.z = f2bf(v.z); o.w = f2bf(v.w);
    xb4[i] = o;
}

// Build WT[c][k] (bf16) and fused bias
__global__ void k_prep_w(const float* __restrict__ Wds, const float* __restrict__ Wsd,
                         const float* __restrict__ bds, const float* __restrict__ bsd,
                         unsigned short* __restrict__ wt, float* __restrict__ bias) {
    int id = blockIdx.x * blockDim.x + threadIdx.x;
    if (id >= 128 * 256) return;
    int c = id & 127;
    int k = id >> 7;
    float v = (k < 128) ? Wds[k * 128 + c] : Wsd[(k - 128) * 128 + c];
    wt[c * 256 + k] = f2bf(v);
    if (k == 0) bias[c] = 0.5f * (bds[c] + bsd[c]);
}

// One 64-lane wave per node: lanes 0-31 = in-direction, 32-63 = out-direction.
__global__ __launch_bounds__(256) void k_gather(
    const ushort4* __restrict__ xb4, const int* __restrict__ offsets,
    const int* __restrict__ csr_src, const float* __restrict__ inv,
    ushort4* __restrict__ agg4) {
    int wave = threadIdx.x >> 6;
    int lane = threadIdx.x & 63;
    int n = blockIdx.x * 4 + wave;
    if (n >= NN) return;
    int grp = lane >> 5;         // 0 = in-agg (keyed by row), 1 = out-agg (keyed by col)
    int cl = lane & 31;

    int key = grp * NN + n;
    int s0 = offsets[key], s1 = offsets[key + 1];

    float4 acc = {0.f, 0.f, 0.f, 0.f};
    for (int base = s0; base < s1; base += 32) {
        int len = s1 - base;
        if (len > 32) len = 32;
        int src_cl = 0;
        float w_cl = 0.f;
        if (cl < len) {
            src_cl = csr_src[base + cl];
            w_cl = inv[(grp ^ 1) * NN + src_cl];   // source-side scale
        }
        for (int j = 0; j < len; ++j) {
            int src = __shfl(src_cl, j, 32);
            float w = __shfl(w_cl, j, 32);
            ushort4 v = xb4[src * 32 + cl];
            acc.x += w * b2f(v.x); acc.y += w * b2f(v.y);
            acc.z += w * b2f(v.z); acc.w += w * b2f(v.w);
        }
    }

    float ds = 0.5f * inv[grp * NN + n];           // dest-side scale + ALPHA fold
    ushort4 o;
    o.x = f2bf(acc.x * ds); o.y = f2bf(acc.y * ds);
    o.z = f2bf(acc.z * ds); o.w = f2bf(acc.w * ds);
    agg4[n * 64 + grp * 32 + cl] = o;
}

// out[N][128] = agg[N][256](bf16) @ WT^T (K=256) + bias
__global__ __launch_bounds__(256) void k_gemm_mfma(
    const unsigned short* __restrict__ agg, const unsigned short* __restrict__ wt,
    const float* __restrict__ bias, float* __restrict__ out) {
    const int wave = threadIdx.x >> 6;
    const int lane = threadIdx.x & 63;
    const int row0 = blockIdx.x * 64 + wave * 16;
    const int fr = lane & 15;
    const int kg = (lane >> 4) * 8;

    int arow = row0 + fr;
    if (arow >= NN) arow = 0;
    const unsigned short* aptr = agg + arow * 256 + kg;

    f32x4 acc[8] = {};

#pragma unroll
    for (int s = 0; s < 8; ++s) {
        short8 afrag = *(const short8*)(aptr + s * 32);
#pragma unroll
        for (int t = 0; t < 8; ++t) {
            short8 bfrag = *(const short8*)(wt + (t * 16 + fr) * 256 + s * 32 + kg);
            acc[t] = __builtin_amdgcn_mfma_f32_16x16x32_bf16(afrag, bfrag, acc[t], 0, 0, 0);
        }
    }

    const int orow0 = row0 + (lane >> 4) * 4;
#pragma unroll
    for (int i = 0; i < 4; ++i) {
        int orow = orow0 + i;
        if (orow < NN) {
#pragma unroll
            for (int t = 0; t < 8; ++t) {
                int col = t * 16 + fr;
                out[orow * 128 + col] = acc[t][i] + bias[col];
            }
        }
    }
}

extern "C" void kernel_launch(void* const* d_in, const int* in_sizes, int n_in,
                              void* d_out, int out_size, void* d_ws, size_t ws_size,
                              hipStream_t stream) {
    const float* x   = (const float*)d_in[0];
    const int* ei    = (const int*)d_in[1];
    const float* Wsd = (const float*)d_in[2];
    const float* bsd = (const float*)d_in[3];
    const float* Wds = (const float*)d_in[4];
    const float* bds = (const float*)d_in[5];

    char* ws = (char*)d_ws;
    float* inv     = (float*)(ws + OFF_INV);
    int*   offsets = (int*)(ws + OFF_OFFS);
    int*   bb      = (int*)(ws + OFF_BB);
    int*   hist    = (int*)(ws + OFF_HIST);
    int*   csr_src = (int*)(ws + OFF_CSRC);
    unsigned short* xb  = (unsigned short*)(ws + OFF_XB);
    unsigned short* agg = (unsigned short*)(ws + OFF_AGG);
    unsigned long long* pairs = (unsigned long long*)(ws + OFF_PAIRS);
    unsigned short* wt  = (unsigned short*)(ws + OFF_WT);
    float* bias    = (float*)(ws + OFF_BIAS);

    k_cvt_x<<<(NN * 32 + 255) / 256, 256, 0, stream>>>((const float4*)x, (ushort4*)xb);
    k_prep_w<<<(128 * 256 + 255) / 256, 256, 0, stream>>>(Wds, Wsd, bds, bsd, wt, bias);
    k_hist<<<256, 256, 0, stream>>>(ei, hist);
    k_scanbase<<<1, 256, 0, stream>>>(hist, bb);
    k_scatter<<<256, 256, 0, stream>>>(ei, hist, pairs);
    k_bucket<<<NB, 256, 0, stream>>>(pairs, bb, csr_src, offsets, inv);
    k_gather<<<(NN + 3) / 4, 256, 0, stream>>>((const ushort4*)xb, offsets, csr_src, inv,
                                               (ushort4*)agg);
    k_gemm_mfma<<<(NN + 63) / 64, 256, 0, stream>>>(agg, wt, bias, (float*)d_out);
}

// Round 5
// 217.098 us; speedup vs baseline: 1.7995x; 1.2066x over previous
//
#include <hip/hip_runtime.h>

#define NN 100000
#define NE 800000
#define NI 1600000      // items = 2E (both directions)
#define NB 391          // coarse buckets = ceil(2N / 512)
#define IPB 6250        // items per block in hist/scatter (256 blocks)

// ---- workspace layout (bytes) ----
#define OFF_INV    0u           // float[2N]   [0,N)=row-keyed counts inv, [N,2N)=col-keyed
#define OFF_OFFS   800000u      // int[2N+1]
#define OFF_BB     1600008u     // int[NB+1]
#define OFF_HIST   1601600u     // int[NB*256]
#define OFF_CSRC   2001984u     // int[2E]
#define OFF_XB     8401984u     // bf16[N*128]
#define OFF_AGG    34001984u    // bf16[N*256] (cols 0..127 = in-agg, 128..255 = out-agg)
#define OFF_PAIRS  34001984u    // ulong[2E] — aliases AGG (dead before k_gather writes agg)
#define OFF_WT     85201984u    // bf16[128*256] WT[c][k]: k<128 -> W_ds, else W_sd
#define OFF_BIAS   85267520u    // float[128] 0.5*(b_ds+b_sd)
#define OFF_TOT    85268032u    // int[NB]

typedef short short8 __attribute__((ext_vector_type(8)));
typedef unsigned short u16x8 __attribute__((ext_vector_type(8)));
typedef float f32x4 __attribute__((ext_vector_type(4)));
typedef float f32x8 __attribute__((ext_vector_type(8)));

__device__ __forceinline__ unsigned short f2bf(float f) {
    unsigned u = __float_as_uint(f);
    u = (u + 0x7FFFu + ((u >> 16) & 1u)) >> 16;   // RNE
    return (unsigned short)u;
}
__device__ __forceinline__ float b2f(unsigned short h) {
    return __uint_as_float(((unsigned)h) << 16);
}
__device__ __forceinline__ f32x8 bvec2f(u16x8 v) {
    f32x8 r;
#pragma unroll
    for (int i = 0; i < 8; ++i) r[i] = b2f(v[i]);
    return r;
}

// item i: i<NE  -> key=row=ei[i],      val=col=ei[NE+i]  (in-agg, keyed by row)
//         i>=NE -> key=NN+col=NN+ei[i], val=row=ei[i-NE] (out-agg, keyed by col)

__global__ __launch_bounds__(256) void k_hist(const int* __restrict__ ei,
                                              int* __restrict__ hist) {
    __shared__ int h[NB];
    for (int k = threadIdx.x; k < NB; k += 256) h[k] = 0;
    __syncthreads();
    int base = blockIdx.x * IPB;
    for (int t = threadIdx.x; t < IPB; t += 256) {
        int i = base + t;
        int key = (i < NE) ? ei[i] : (NN + ei[i]);
        atomicAdd(&h[key >> 9], 1);
    }
    __syncthreads();
    for (int k = threadIdx.x; k < NB; k += 256) hist[k * 256 + blockIdx.x] = h[k];
}

// tot[k] = sum_b hist[k][b]
__global__ __launch_bounds__(256) void k_red(const int* __restrict__ hist,
                                             int* __restrict__ tot) {
    __shared__ int s[256];
    int k = blockIdx.x;
    s[threadIdx.x] = hist[k * 256 + threadIdx.x];
    __syncthreads();
    for (int st = 128; st > 0; st >>= 1) {
        if (threadIdx.x < st) s[threadIdx.x] += s[threadIdx.x + st];
        __syncthreads();
    }
    if (threadIdx.x == 0) tot[k] = s[0];
}

// bb = exclusive scan of tot (NB entries, padded to 512)
__global__ __launch_bounds__(512) void k_scan_tot(const int* __restrict__ tot,
                                                  int* __restrict__ bb) {
    __shared__ int sA[512], sB[512];
    int tid = threadIdx.x;
    int v = (tid < NB) ? tot[tid] : 0;
    sA[tid] = v;
    __syncthreads();
    int *src = sA, *dst = sB;
    for (int st = 1; st < 512; st <<= 1) {
        dst[tid] = src[tid] + ((tid >= st) ? src[tid - st] : 0);
        __syncthreads();
        int* tp = src; src = dst; dst = tp;
    }
    if (tid <= NB) bb[tid] = (tid > 0) ? src[tid - 1] : 0;
}

// hist[k][b] = bb[k] + exclusive_scan_b(hist[k][*])
__global__ __launch_bounds__(256) void k_rebase(int* __restrict__ hist,
                                                const int* __restrict__ bb) {
    __shared__ int sA[256], sB[256];
    int k = blockIdx.x, tid = threadIdx.x;
    int v = hist[k * 256 + tid];
    sA[tid] = v;
    __syncthreads();
    int *src = sA, *dst = sB;
    for (int st = 1; st < 256; st <<= 1) {
        dst[tid] = src[tid] + ((tid >= st) ? src[tid - st] : 0);
        __syncthreads();
        int* tp = src; src = dst; dst = tp;
    }
    hist[k * 256 + tid] = bb[k] + src[tid] - v;   // exclusive
}

__global__ __launch_bounds__(256) void k_scatter(const int* __restrict__ ei,
                                                 const int* __restrict__ hist,
                                                 unsigned long long* __restrict__ pairs) {
    __shared__ int cur[NB];
    for (int k = threadIdx.x; k < NB; k += 256) cur[k] = hist[k * 256 + blockIdx.x];
    __syncthreads();
    int base = blockIdx.x * IPB;
    for (int t = threadIdx.x; t < IPB; t += 256) {
        int i = base + t;
        int e = ei[i];
        int key, val;
        if (i < NE) { key = e;      val = ei[NE + i]; }
        else        { key = NN + e; val = ei[i - NE]; }
        int pos = atomicAdd(&cur[key >> 9], 1);
        pairs[pos] = (((unsigned long long)(unsigned)key) << 32) | (unsigned)val;
    }
}

// one block per bucket: count 512 local keys, scan, emit offsets+inv, scatter vals
__global__ __launch_bounds__(256) void k_bucket(const unsigned long long* __restrict__ pairs,
                                                const int* __restrict__ bb,
                                                int* __restrict__ csr_src,
                                                int* __restrict__ offsets,
                                                float* __restrict__ inv) {
    __shared__ int sA[512], sB[512], cur[512];
    const int h = blockIdx.x, tid = threadIdx.x;
    const int s0 = bb[h], s1 = bb[h + 1];
    for (int k = tid; k < 512; k += 256) sA[k] = 0;
    __syncthreads();
    for (int i = s0 + tid; i < s1; i += 256) {
        int key = (int)(pairs[i] >> 32);
        atomicAdd(&sA[key & 511], 1);
    }
    __syncthreads();
    int *src = sA, *dst = sB;
    for (int st = 1; st < 512; st <<= 1) {
        for (int k = tid; k < 512; k += 256) dst[k] = src[k] + ((k >= st) ? src[k - st] : 0);
        __syncthreads();
        int* tp = src; src = dst; dst = tp;
    }
    // src = inclusive scan
    for (int k = tid; k < 512; k += 256) {
        int incl = src[k];
        int excl = (k > 0) ? src[k - 1] : 0;
        cur[k] = s0 + excl;
        int gkey = h * 512 + k;
        if (gkey <= 2 * NN) offsets[gkey] = s0 + excl;
        if (gkey < 2 * NN) {
            int cnt = incl - excl;
            inv[gkey] = (cnt > 0) ? rsqrtf((float)cnt) : 0.0f;
        }
    }
    __syncthreads();
    for (int i = s0 + tid; i < s1; i += 256) {
        unsigned long long p = pairs[i];
        int key = (int)(p >> 32);
        int pos = atomicAdd(&cur[key & 511], 1);
        csr_src[pos] = (int)(unsigned)(p & 0xffffffffULL);
    }
}

// x fp32 -> bf16
__global__ __launch_bounds__(256) void k_cvt_x(const float4* __restrict__ x4,
                                               ushort4* __restrict__ xb4) {
    int i = blockIdx.x * blockDim.x + threadIdx.x;
    if (i >= NN * 32) return;
    float4 v = x4[i];
    ushort4 o;
    o.x = f2bf(v.x); o.y = f2bf(v.y); o.z = f2bf(v.z); o.w = f2bf(v.w);
    xb4[i] = o;
}

// Build WT[c][k] (bf16) and fused bias
__global__ void k_prep_w(const float* __restrict__ Wds, const float* __restrict__ Wsd,
                         const float* __restrict__ bds, const float* __restrict__ bsd,
                         unsigned short* __restrict__ wt, float* __restrict__ bias) {
    int id = blockIdx.x * blockDim.x + threadIdx.x;
    if (id >= 128 * 256) return;
    int c = id & 127;
    int k = id >> 7;
    float v = (k < 128) ? Wds[k * 128 + c] : Wsd[(k - 128) * 128 + c];
    wt[c * 256 + k] = f2bf(v);
    if (k == 0) bias[c] = 0.5f * (bds[c] + bsd[c]);
}

// Wave = 4 groups of 16 lanes (2 nodes x 2 directions). 16 lanes x ushort8 = one row.
// csr/inv reads are same-address within a group (L1 broadcast); 4x unroll gives
// 4 independent row-load chains per group = 16 outstanding loads per wave.
__global__ __launch_bounds__(256) void k_gather(
    const u16x8* __restrict__ xb8, const int* __restrict__ offsets,
    const int* __restrict__ csr_src, const float* __restrict__ inv,
    u16x8* __restrict__ agg8) {
    int wave = threadIdx.x >> 6;
    int lane = threadIdx.x & 63;
    int grp = lane >> 4;                 // 0..3
    int cl = lane & 15;
    int n = blockIdx.x * 8 + wave * 2 + (grp >> 1);   // 12500*8 == NN exactly
    int dir = grp & 1;                   // 0 = in-agg (row-keyed), 1 = out-agg (col-keyed)

    int key = dir * NN + n;
    int s0 = offsets[key], s1 = offsets[key + 1];
    const float* __restrict__ srcinv = inv + (dir ^ 1) * NN;

    f32x8 acc = {0.f, 0.f, 0.f, 0.f, 0.f, 0.f, 0.f, 0.f};
    int e = s0;
    for (; e + 4 <= s1; e += 4) {
        int i0 = csr_src[e];
        int i1 = csr_src[e + 1];
        int i2 = csr_src[e + 2];
        int i3 = csr_src[e + 3];
        float w0 = srcinv[i0], w1 = srcinv[i1], w2 = srcinv[i2], w3 = srcinv[i3];
        u16x8 v0 = xb8[i0 * 16 + cl];
        u16x8 v1 = xb8[i1 * 16 + cl];
        u16x8 v2 = xb8[i2 * 16 + cl];
        u16x8 v3 = xb8[i3 * 16 + cl];
        acc += w0 * bvec2f(v0);
        acc += w1 * bvec2f(v1);
        acc += w2 * bvec2f(v2);
        acc += w3 * bvec2f(v3);
    }
    for (; e < s1; ++e) {
        int i0 = csr_src[e];
        float w0 = srcinv[i0];
        u16x8 v0 = xb8[i0 * 16 + cl];
        acc += w0 * bvec2f(v0);
    }

    float ds = 0.5f * inv[dir * NN + n];           // dest-side scale + ALPHA fold
    u16x8 o;
#pragma unroll
    for (int i = 0; i < 8; ++i) o[i] = f2bf(acc[i] * ds);
    agg8[n * 32 + dir * 16 + cl] = o;
}

// out[N][128] = agg[N][256](bf16) @ WT^T (K=256) + bias
__global__ __launch_bounds__(256) void k_gemm_mfma(
    const unsigned short* __restrict__ agg, const unsigned short* __restrict__ wt,
    const float* __restrict__ bias, float* __restrict__ out) {
    const int wave = threadIdx.x >> 6;
    const int lane = threadIdx.x & 63;
    const int row0 = blockIdx.x * 64 + wave * 16;
    const int fr = lane & 15;
    const int kg = (lane >> 4) * 8;

    int arow = row0 + fr;
    if (arow >= NN) arow = 0;
    const unsigned short* aptr = agg + arow * 256 + kg;

    f32x4 acc[8] = {};

#pragma unroll
    for (int s = 0; s < 8; ++s) {
        short8 afrag = *(const short8*)(aptr + s * 32);
#pragma unroll
        for (int t = 0; t < 8; ++t) {
            short8 bfrag = *(const short8*)(wt + (t * 16 + fr) * 256 + s * 32 + kg);
            acc[t] = __builtin_amdgcn_mfma_f32_16x16x32_bf16(afrag, bfrag, acc[t], 0, 0, 0);
        }
    }

    const int orow0 = row0 + (lane >> 4) * 4;
#pragma unroll
    for (int i = 0; i < 4; ++i) {
        int orow = orow0 + i;
        if (orow < NN) {
#pragma unroll
            for (int t = 0; t < 8; ++t) {
                int col = t * 16 + fr;
                out[orow * 128 + col] = acc[t][i] + bias[col];
            }
        }
    }
}

extern "C" void kernel_launch(void* const* d_in, const int* in_sizes, int n_in,
                              void* d_out, int out_size, void* d_ws, size_t ws_size,
                              hipStream_t stream) {
    const float* x   = (const float*)d_in[0];
    const int* ei    = (const int*)d_in[1];
    const float* Wsd = (const float*)d_in[2];
    const float* bsd = (const float*)d_in[3];
    const float* Wds = (const float*)d_in[4];
    const float* bds = (const float*)d_in[5];

    char* ws = (char*)d_ws;
    float* inv     = (float*)(ws + OFF_INV);
    int*   offsets = (int*)(ws + OFF_OFFS);
    int*   bb      = (int*)(ws + OFF_BB);
    int*   hist    = (int*)(ws + OFF_HIST);
    int*   csr_src = (int*)(ws + OFF_CSRC);
    unsigned short* xb  = (unsigned short*)(ws + OFF_XB);
    unsigned short* agg = (unsigned short*)(ws + OFF_AGG);
    unsigned long long* pairs = (unsigned long long*)(ws + OFF_PAIRS);
    unsigned short* wt  = (unsigned short*)(ws + OFF_WT);
    float* bias    = (float*)(ws + OFF_BIAS);
    int*   tot     = (int*)(ws + OFF_TOT);

    k_cvt_x<<<(NN * 32 + 255) / 256, 256, 0, stream>>>((const float4*)x, (ushort4*)xb);
    k_prep_w<<<(128 * 256 + 255) / 256, 256, 0, stream>>>(Wds, Wsd, bds, bsd, wt, bias);
    k_hist<<<256, 256, 0, stream>>>(ei, hist);
    k_red<<<NB, 256, 0, stream>>>(hist, tot);
    k_scan_tot<<<1, 512, 0, stream>>>(tot, bb);
    k_rebase<<<NB, 256, 0, stream>>>(hist, bb);
    k_scatter<<<256, 256, 0, stream>>>(ei, hist, pairs);
    k_bucket<<<NB, 256, 0, stream>>>(pairs, bb, csr_src, offsets, inv);
    k_gather<<<NN / 8, 256, 0, stream>>>((const u16x8*)xb, offsets, csr_src, inv,
                                         (u16x8*)agg);
    k_gemm_mfma<<<(NN + 63) / 64, 256, 0, stream>>>(agg, wt, bias, (float*)d_out);
}

// Round 6
// 179.456 us; speedup vs baseline: 2.1769x; 1.2098x over previous
//
#include <hip/hip_runtime.h>

#define NN 100000
#define NE 800000
#define NI 1600000      // items = 2E (both directions)
#define NB 391          // coarse buckets = ceil(2N / 512)
#define IPB 6250        // items per block in hist/scatter (256 blocks)

// grid split for fused prep kernel
#define GB_CVT 12500    // cvt_x blocks (NN*32 float4 / 256)
#define GB_PW  128      // prep_w blocks
#define GB_HIST 256     // hist blocks

// ---- workspace layout (bytes) ----
#define OFF_INV    0u           // float[2N]   [0,N)=row-keyed inv, [N,2N)=col-keyed inv
#define OFF_OFFS   800000u      // int[2N+1]
#define OFF_BB     1600008u     // int[NB+1]
#define OFF_HIST   1601600u     // int[NB*256]
#define OFF_CSRC   2001984u     // int[2E]
#define OFF_XB     8401984u     // bf16[N*128]
#define OFF_PAIRS  34001984u    // ulong[2E]
#define OFF_WT     85201984u    // bf16[128*256] WT[c][k]: k<128 -> W_ds, else W_sd
#define OFF_BIAS   85267520u    // float[128] 0.5*(b_ds+b_sd)
#define OFF_TOT    85268032u    // int[NB]

typedef short short8 __attribute__((ext_vector_type(8)));
typedef unsigned short u16x8 __attribute__((ext_vector_type(8)));
typedef float f32x4 __attribute__((ext_vector_type(4)));
typedef float f32x8 __attribute__((ext_vector_type(8)));

__device__ __forceinline__ unsigned short f2bf(float f) {
    unsigned u = __float_as_uint(f);
    u = (u + 0x7FFFu + ((u >> 16) & 1u)) >> 16;   // RNE
    return (unsigned short)u;
}
__device__ __forceinline__ float b2f(unsigned short h) {
    return __uint_as_float(((unsigned)h) << 16);
}
__device__ __forceinline__ f32x8 bvec2f(u16x8 v) {
    f32x8 r;
#pragma unroll
    for (int i = 0; i < 8; ++i) r[i] = b2f(v[i]);
    return r;
}

// item i: i<NE  -> key=row=ei[i],      val=col=ei[NE+i]  (in-agg, keyed by row)
//         i>=NE -> key=NN+col=NN+ei[i], val=row=ei[i-NE] (out-agg, keyed by col)

// Fused: cvt_x (blocks [0,GB_CVT)) | prep_w | hist  — mutually independent work
__global__ __launch_bounds__(256) void k_prep(
    const float4* __restrict__ x4, ushort4* __restrict__ xb4,
    const float* __restrict__ Wds, const float* __restrict__ Wsd,
    const float* __restrict__ bds, const float* __restrict__ bsd,
    unsigned short* __restrict__ wt, float* __restrict__ bias,
    const int* __restrict__ ei, int* __restrict__ hist) {
    __shared__ int h[NB];
    int bid = blockIdx.x;
    if (bid < GB_CVT) {
        int i = bid * 256 + threadIdx.x;           // < NN*32 exactly
        float4 v = x4[i];
        ushort4 o;
        o.x = f2bf(v.x); o.y = f2bf(v.y); o.z = f2bf(v.z); o.w = f2bf(v.w);
        xb4[i] = o;
        return;
    }
    if (bid < GB_CVT + GB_PW) {
        int id = (bid - GB_CVT) * 256 + threadIdx.x;   // < 32768 exactly
        int c = id & 127;
        int k = id >> 7;
        float v = (k < 128) ? Wds[k * 128 + c] : Wsd[(k - 128) * 128 + c];
        wt[c * 256 + k] = f2bf(v);
        if (k == 0) bias[c] = 0.5f * (bds[c] + bsd[c]);
        return;
    }
    int hb = bid - GB_CVT - GB_PW;                  // hist block 0..255
    for (int k = threadIdx.x; k < NB; k += 256) h[k] = 0;
    __syncthreads();
    int base = hb * IPB;
    for (int t = threadIdx.x; t < IPB; t += 256) {
        int i = base + t;
        int key = (i < NE) ? ei[i] : (NN + ei[i]);
        atomicAdd(&h[key >> 9], 1);
    }
    __syncthreads();
    for (int k = threadIdx.x; k < NB; k += 256) hist[k * 256 + hb] = h[k];
}

// tot[k] = sum_b hist[k][b]
__global__ __launch_bounds__(256) void k_red(const int* __restrict__ hist,
                                             int* __restrict__ tot) {
    __shared__ int s[256];
    int k = blockIdx.x;
    s[threadIdx.x] = hist[k * 256 + threadIdx.x];
    __syncthreads();
    for (int st = 128; st > 0; st >>= 1) {
        if (threadIdx.x < st) s[threadIdx.x] += s[threadIdx.x + st];
        __syncthreads();
    }
    if (threadIdx.x == 0) tot[k] = s[0];
}

// bb = exclusive scan of tot (NB entries, padded to 512)
__global__ __launch_bounds__(512) void k_scan_tot(const int* __restrict__ tot,
                                                  int* __restrict__ bb) {
    __shared__ int sA[512], sB[512];
    int tid = threadIdx.x;
    int v = (tid < NB) ? tot[tid] : 0;
    sA[tid] = v;
    __syncthreads();
    int *src = sA, *dst = sB;
    for (int st = 1; st < 512; st <<= 1) {
        dst[tid] = src[tid] + ((tid >= st) ? src[tid - st] : 0);
        __syncthreads();
        int* tp = src; src = dst; dst = tp;
    }
    if (tid <= NB) bb[tid] = (tid > 0) ? src[tid - 1] : 0;
}

// hist[k][b] = bb[k] + exclusive_scan_b(hist[k][*])
__global__ __launch_bounds__(256) void k_rebase(int* __restrict__ hist,
                                                const int* __restrict__ bb) {
    __shared__ int sA[256], sB[256];
    int k = blockIdx.x, tid = threadIdx.x;
    int v = hist[k * 256 + tid];
    sA[tid] = v;
    __syncthreads();
    int *src = sA, *dst = sB;
    for (int st = 1; st < 256; st <<= 1) {
        dst[tid] = src[tid] + ((tid >= st) ? src[tid - st] : 0);
        __syncthreads();
        int* tp = src; src = dst; dst = tp;
    }
    hist[k * 256 + tid] = bb[k] + src[tid] - v;   // exclusive
}

__global__ __launch_bounds__(256) void k_scatter(const int* __restrict__ ei,
                                                 const int* __restrict__ hist,
                                                 unsigned long long* __restrict__ pairs) {
    __shared__ int cur[NB];
    for (int k = threadIdx.x; k < NB; k += 256) cur[k] = hist[k * 256 + blockIdx.x];
    __syncthreads();
    int base = blockIdx.x * IPB;
    for (int t = threadIdx.x; t < IPB; t += 256) {
        int i = base + t;
        int e = ei[i];
        int key, val;
        if (i < NE) { key = e;      val = ei[NE + i]; }
        else        { key = NN + e; val = ei[i - NE]; }
        int pos = atomicAdd(&cur[key >> 9], 1);
        pairs[pos] = (((unsigned long long)(unsigned)key) << 32) | (unsigned)val;
    }
}

// one block per bucket: count 512 local keys, scan, emit offsets+inv, scatter vals
__global__ __launch_bounds__(256) void k_bucket(const unsigned long long* __restrict__ pairs,
                                                const int* __restrict__ bb,
                                                int* __restrict__ csr_src,
                                                int* __restrict__ offsets,
                                                float* __restrict__ inv) {
    __shared__ int sA[512], sB[512], cur[512];
    const int h = blockIdx.x, tid = threadIdx.x;
    const int s0 = bb[h], s1 = bb[h + 1];
    for (int k = tid; k < 512; k += 256) sA[k] = 0;
    __syncthreads();
    for (int i = s0 + tid; i < s1; i += 256) {
        int key = (int)(pairs[i] >> 32);
        atomicAdd(&sA[key & 511], 1);
    }
    __syncthreads();
    int *src = sA, *dst = sB;
    for (int st = 1; st < 512; st <<= 1) {
        for (int k = tid; k < 512; k += 256) dst[k] = src[k] + ((k >= st) ? src[k - st] : 0);
        __syncthreads();
        int* tp = src; src = dst; dst = tp;
    }
    // src = inclusive scan
    for (int k = tid; k < 512; k += 256) {
        int incl = src[k];
        int excl = (k > 0) ? src[k - 1] : 0;
        cur[k] = s0 + excl;
        int gkey = h * 512 + k;
        if (gkey <= 2 * NN) offsets[gkey] = s0 + excl;
        if (gkey < 2 * NN) {
            int cnt = incl - excl;
            inv[gkey] = (cnt > 0) ? rsqrtf((float)cnt) : 0.0f;
        }
    }
    __syncthreads();
    for (int i = s0 + tid; i < s1; i += 256) {
        unsigned long long p = pairs[i];
        int key = (int)(p >> 32);
        int pos = atomicAdd(&cur[key & 511], 1);
        csr_src[pos] = (int)(unsigned)(p & 0xffffffffULL);
    }
}

// Fused gather + GEMM. Block = 512 threads (8 waves) = 16 nodes.
// Gather phase: wave w covers nodes 2w,2w+1 x 2 dirs in 4 groups of 16 lanes;
//   agg row (bf16) goes to LDS [16][264] (+8 pad -> 2-way banks, free).
// GEMM phase: wave w computes col-tile w (16 cols) for all 16 nodes:
//   8 x mfma_16x16x32, A from LDS, B streamed from L2-hot WT (64 KB).
__global__ __launch_bounds__(512) void k_gather_gemm(
    const u16x8* __restrict__ xb8, const int* __restrict__ offsets,
    const int* __restrict__ csr_src, const float* __restrict__ inv,
    const unsigned short* __restrict__ wt, const float* __restrict__ bias,
    float* __restrict__ out) {
    __shared__ unsigned short a_lds[16][264];

    const int wave = threadIdx.x >> 6;
    const int lane = threadIdx.x & 63;
    const int grp = lane >> 4;                 // 0..3
    const int cl = lane & 15;
    const int nl = wave * 2 + (grp >> 1);      // local node 0..15
    const int n = blockIdx.x * 16 + nl;        // 6250*16 == NN exactly
    const int dir = grp & 1;                   // 0 = in-agg, 1 = out-agg

    {
        int key = dir * NN + n;
        int s0 = offsets[key], s1 = offsets[key + 1];
        const float* __restrict__ srcinv = inv + (dir ^ 1) * NN;

        f32x8 acc = {0.f, 0.f, 0.f, 0.f, 0.f, 0.f, 0.f, 0.f};
        int e = s0;
        for (; e + 4 <= s1; e += 4) {
            int i0 = csr_src[e];
            int i1 = csr_src[e + 1];
            int i2 = csr_src[e + 2];
            int i3 = csr_src[e + 3];
            float w0 = srcinv[i0], w1 = srcinv[i1], w2 = srcinv[i2], w3 = srcinv[i3];
            u16x8 v0 = xb8[i0 * 16 + cl];
            u16x8 v1 = xb8[i1 * 16 + cl];
            u16x8 v2 = xb8[i2 * 16 + cl];
            u16x8 v3 = xb8[i3 * 16 + cl];
            acc += w0 * bvec2f(v0);
            acc += w1 * bvec2f(v1);
            acc += w2 * bvec2f(v2);
            acc += w3 * bvec2f(v3);
        }
        for (; e < s1; ++e) {
            int i0 = csr_src[e];
            float w0 = srcinv[i0];
            u16x8 v0 = xb8[i0 * 16 + cl];
            acc += w0 * bvec2f(v0);
        }

        float ds = 0.5f * inv[dir * NN + n];       // dest-side scale + ALPHA fold
        u16x8 o;
#pragma unroll
        for (int i = 0; i < 8; ++i) o[i] = f2bf(acc[i] * ds);
        *(u16x8*)&a_lds[nl][dir * 128 + cl * 8] = o;
    }
    __syncthreads();

    // GEMM: this wave's 16x16 output tile, cols [wave*16, wave*16+16)
    const int fr = lane & 15;
    const int kg = (lane >> 4) * 8;
    const int col = wave * 16 + fr;

    f32x4 acc = {};
#pragma unroll
    for (int s = 0; s < 8; ++s) {
        short8 afrag = *(const short8*)&a_lds[fr][s * 32 + kg];
        short8 bfrag = *(const short8*)(wt + col * 256 + s * 32 + kg);
        acc = __builtin_amdgcn_mfma_f32_16x16x32_bf16(afrag, bfrag, acc, 0, 0, 0);
    }

    const float b = bias[col];
    const int orow0 = blockIdx.x * 16 + (lane >> 4) * 4;
#pragma unroll
    for (int i = 0; i < 4; ++i) {
        out[(orow0 + i) * 128 + col] = acc[i] + b;
    }
}

extern "C" void kernel_launch(void* const* d_in, const int* in_sizes, int n_in,
                              void* d_out, int out_size, void* d_ws, size_t ws_size,
                              hipStream_t stream) {
    const float* x   = (const float*)d_in[0];
    const int* ei    = (const int*)d_in[1];
    const float* Wsd = (const float*)d_in[2];
    const float* bsd = (const float*)d_in[3];
    const float* Wds = (const float*)d_in[4];
    const float* bds = (const float*)d_in[5];

    char* ws = (char*)d_ws;
    float* inv     = (float*)(ws + OFF_INV);
    int*   offsets = (int*)(ws + OFF_OFFS);
    int*   bb      = (int*)(ws + OFF_BB);
    int*   hist    = (int*)(ws + OFF_HIST);
    int*   csr_src = (int*)(ws + OFF_CSRC);
    unsigned short* xb  = (unsigned short*)(ws + OFF_XB);
    unsigned long long* pairs = (unsigned long long*)(ws + OFF_PAIRS);
    unsigned short* wt  = (unsigned short*)(ws + OFF_WT);
    float* bias    = (float*)(ws + OFF_BIAS);
    int*   tot     = (int*)(ws + OFF_TOT);

    k_prep<<<GB_CVT + GB_PW + GB_HIST, 256, 0, stream>>>(
        (const float4*)x, (ushort4*)xb, Wds, Wsd, bds, bsd, wt, bias, ei, hist);
    k_red<<<NB, 256, 0, stream>>>(hist, tot);
    k_scan_tot<<<1, 512, 0, stream>>>(tot, bb);
    k_rebase<<<NB, 256, 0, stream>>>(hist, bb);
    k_scatter<<<256, 256, 0, stream>>>(ei, hist, pairs);
    k_bucket<<<NB, 256, 0, stream>>>(pairs, bb, csr_src, offsets, inv);
    k_gather_gemm<<<NN / 16, 512, 0, stream>>>((const u16x8*)xb, offsets, csr_src, inv,
                                               wt, bias, (float*)d_out);
}